// Round 15
// baseline (13626.674 us; speedup 1.0000x reference)
//
#include <hip/hip_runtime.h>

// GRU  B=128, T=1024, IN=256, H=512, OUT=1  (all fp32)
//
// v14 = v13's validated MFMA math + minimum-dependency sync:
//  - B-frags (x and h) loaded per-wave DIRECTLY global->registers (frag lane
//    layout (s=lane&15, k=8*(lane>>4)+i) == plain 32B/lane load). No U in
//    LDS, no staging barriers (v13's P and B deleted).
//  - per-wave producer polling: wave w8 needs h-chunks {3w8..3w8+2}&[8,24),
//    produced by wgs 2(c-8),2(c-8)+1 -> <=6 flags polled lane-parallel by
//    the wave itself. Waves 0-1 (x-only) never poll.
//  - ONE __syncthreads per step (partials barrier C). Rotating gate wave
//    (w8 == t&7): reads ds_add-accumulated sums from a DOUBLE-BUFFERED acc,
//    zeroes the buffer for t+2, computes gates, sc-stores packed hnew
//    (coalesced 4x64B rows), vmcnt(0), sets flag. Other waves free-run into
//    t+1; dbuf + barrier-C induction makes it race-free.
//  - split-bf16 3-pass MFMA, A-hi in VGPRs, A-lo in LDS, packed (hi<<16|lo)
//    h format: v13-verbatim (passed, absmax 0).

#define B_    128
#define T_    1024
#define IN_   256
#define H_    512
#define NG    8
#define WPG   32
#define SGRP  16
#define JT    16
#define NT    512
#define ACC_OFF  (8*9*64*16)             // Wlo = 73,728 B
#define LDS_DYN  (ACC_OFF + 2*4*16*17*4) // + 8,704 B acc = 82,432 B

typedef __attribute__((ext_vector_type(8))) short bf16x8;
typedef __attribute__((ext_vector_type(4))) float f32x4;
union BCast { uint4 u; bf16x8 b; unsigned short s[8]; };

#define MFMA(a,b,c) __builtin_amdgcn_mfma_f32_16x16x32_bf16((a),(b),(c),0,0,0)

__device__ __forceinline__ float sig_(float v){ return 1.0f/(1.0f + __expf(-v)); }
__device__ __forceinline__ float tanh_(float v){
  float e = __expf(2.0f*v);
  return 1.0f - 2.0f/(e + 1.0f);
}
__device__ __forceinline__ unsigned short bf16rn(float f){
  unsigned u = __float_as_uint(f);
  return (unsigned short)((u + 0x7FFFu + ((u>>16)&1u)) >> 16);
}

// IF-coherent ops (sc0 sc1). Data operands <=64-bit except 128-bit OUTPUTS.
#define CLOADU4(dst, p) asm volatile("global_load_dwordx4 %0, %1, off sc0 sc1" : "=v"(dst) : "v"(p) : "memory")
#define CLOADI(dst, p)  asm volatile("global_load_dword %0, %1, off sc0 sc1"   : "=v"(dst) : "v"(p) : "memory")
#define CSTOREU(p, v)   asm volatile("global_store_dword %0, %1, off sc0 sc1"  :: "v"(p), "v"(v) : "memory")
#define VWAIT0()        do{ asm volatile("s_waitcnt vmcnt(0)" ::: "memory"); __builtin_amdgcn_sched_barrier(0); }while(0)

__global__ void __launch_bounds__(NT, 2)
rnn_persist(const float* __restrict__ x, const float* __restrict__ W_ih,
            const float* __restrict__ W_hh, const float* __restrict__ bias,
            const float* __restrict__ bias_n, unsigned* __restrict__ h_buf,
            int* __restrict__ flags)
{
  extern __shared__ char lds[];
  char*  Wlo  = lds;
  float* accb = (float*)(lds + ACC_OFF);

  const int bid = (int)blockIdx.x;
  const int g   = bid & (NG-1);
  const int w   = bid >> 3;
  const int tid = (int)threadIdx.x;
  const int w8  = tid >> 6;            // wave [0,8)
  const int l   = tid & 63;
  const int jl  = l & 15;
  const int kq  = l >> 4;
  const int b0  = g*SGRP;
  const int jg_l = w*JT + jl;

  // ---- A-frags: hi -> VGPRs, lo -> LDS (v13-verbatim) ----
  bf16x8 ahi[9];
#pragma unroll
  for (int ci=0; ci<3; ci++){
    const int c = 3*w8 + ci;
#pragma unroll
    for (int gi=0; gi<3; gi++){
      const int f = 3*ci + gi;
      const int grow = gi*H_ + jg_l;
      const float* p = (c < 8)
        ? (W_ih + (size_t)grow*IN_ + (32*c + 8*kq))
        : (W_hh + (size_t)grow*H_  + (32*c - 256 + 8*kq));
      const float4 v0 = *(const float4*)p;
      const float4 v1 = *(const float4*)(p+4);
      const float vv[8] = {v0.x,v0.y,v0.z,v0.w,v1.x,v1.y,v1.z,v1.w};
      BCast hi8, lo8;
#pragma unroll
      for (int i=0;i<8;i++){
        const unsigned short h = bf16rn(vv[i]);
        hi8.s[i] = h;
        lo8.s[i] = bf16rn(vv[i] - __uint_as_float(((unsigned)h)<<16));
      }
      ahi[f] = hi8.b;
      *(bf16x8*)(Wlo + ((size_t)(w8*9 + f)*64 + l)*16) = lo8.b;
    }
  }
  // biases (gate j == jl)
  const int jj = w*JT + jl;
  const float br = bias[jj], bz = bias[H_+jj], bni = bias[2*H_+jj], bnh = bias_n[jj];

  // zero both acc buffers
  for (int i=tid; i<2*4*16*17; i+=NT) accb[i] = 0.f;
  __syncthreads();

  // per-wave producer-flag set: h-chunks [max(8,3w8), 3w8+3) -> wgs
  const int ch0 = (3*w8 < 8) ? 8 : 3*w8;
  const int np  = (3*w8+3 > 8) ? 2*(3*w8+3-ch0) : 0;
  const int p0  = 2*(ch0-8);
  const int* mypf = flags + g*WPG + p0 + ((l < np) ? l : 0);

  unsigned* const hb0 = h_buf;
  unsigned* const hb1 = h_buf + (size_t)B_*H_;
  int dead = 0;

  for (int t=0; t<T_; ++t){
    const unsigned* hc = (t & 1) ? hb1 : hb0;
    unsigned*      hnx = (t & 1) ? hb0 : hb1;
    const int pb = (t & 1) * 1088;     // acc dbuf base

    // ---- x-frags: plain cached loads + convert (flag-independent) ----
    bf16x8 bxh[3], bxl[3];
#pragma unroll
    for (int ci=0; ci<3; ci++){
      const int c = 3*w8 + ci;
      if (c < 8){
        const float* xp = x + ((size_t)(b0+jl)*T_ + (size_t)t)*IN_ + 32*c + 8*kq;
        const float4 a = *(const float4*)xp;
        const float4 b = *(const float4*)(xp+4);
        const float vv[8] = {a.x,a.y,a.z,a.w,b.x,b.y,b.z,b.w};
        BCast hi8, lo8;
#pragma unroll
        for (int i=0;i<8;i++){
          const unsigned short h = bf16rn(vv[i]);
          hi8.s[i] = h;
          lo8.s[i] = bf16rn(vv[i] - __uint_as_float(((unsigned)h)<<16));
        }
        bxh[ci] = hi8.b; bxl[ci] = lo8.b;
      }
    }

    // ---- per-wave poll of my <=6 producers ----
    if (t > 0 && np > 0 && !dead){
      int guard = 0;
      for (;;){
        int fv; CLOADI(fv, mypf);
        asm volatile("s_waitcnt vmcnt(0)" ::: "memory");
        if (__all(fv >= t)) break;
        __builtin_amdgcn_s_sleep(4);
        if (++guard > (1<<21)) { dead = 1; break; }
      }
      __builtin_amdgcn_sched_barrier(0);
    }

    // ---- h-frags: sc loads direct to registers ----
    uint4 hA[3], hB[3];
#pragma unroll
    for (int ci=0; ci<3; ci++){
      const int c = 3*w8 + ci;
      if (c >= 8){
        const unsigned* hp = hc + (size_t)(b0+jl)*H_ + 32*(c-8) + 8*kq;
        CLOADU4(hA[ci], hp); CLOADU4(hB[ci], (hp+4));
      }
    }
    VWAIT0();

    // ---- MFMA: 3 chunks x {r,z,ni|nh} x 3 passes (v13 math) ----
    f32x4 cR={0,0,0,0}, cZ={0,0,0,0}, cNI={0,0,0,0}, cNH={0,0,0,0};
#pragma unroll
    for (int ci=0; ci<3; ci++){
      const int c = 3*w8 + ci;
      bf16x8 bhi, blo;
      if (c < 8){ bhi = bxh[ci]; blo = bxl[ci]; }
      else {
        const unsigned P[8] = {hA[ci].x,hA[ci].y,hA[ci].z,hA[ci].w,
                               hB[ci].x,hB[ci].y,hB[ci].z,hB[ci].w};
        BCast hw, lw;
        hw.u = make_uint4((P[0]>>16)|(P[1]&0xFFFF0000u), (P[2]>>16)|(P[3]&0xFFFF0000u),
                          (P[4]>>16)|(P[5]&0xFFFF0000u), (P[6]>>16)|(P[7]&0xFFFF0000u));
        lw.u = make_uint4((P[0]&0xFFFFu)|(P[1]<<16), (P[2]&0xFFFFu)|(P[3]<<16),
                          (P[4]&0xFFFFu)|(P[5]<<16), (P[6]&0xFFFFu)|(P[7]<<16));
        bhi = hw.b; blo = lw.b;
      }
      const bf16x8 aloR = *(const bf16x8*)(Wlo + ((size_t)(w8*9+3*ci+0)*64 + l)*16);
      const bf16x8 aloZ = *(const bf16x8*)(Wlo + ((size_t)(w8*9+3*ci+1)*64 + l)*16);
      const bf16x8 aloN = *(const bf16x8*)(Wlo + ((size_t)(w8*9+3*ci+2)*64 + l)*16);
      cR = MFMA(ahi[3*ci+0], bhi, cR);
      cR = MFMA(ahi[3*ci+0], blo, cR);
      cR = MFMA(aloR,        bhi, cR);
      cZ = MFMA(ahi[3*ci+1], bhi, cZ);
      cZ = MFMA(ahi[3*ci+1], blo, cZ);
      cZ = MFMA(aloZ,        bhi, cZ);
      if (c < 8){
        cNI = MFMA(ahi[3*ci+2], bhi, cNI);
        cNI = MFMA(ahi[3*ci+2], blo, cNI);
        cNI = MFMA(aloN,        bhi, cNI);
      } else {
        cNH = MFMA(ahi[3*ci+2], bhi, cNH);
        cNH = MFMA(ahi[3*ci+2], blo, cNH);
        cNH = MFMA(aloN,        bhi, cNH);
      }
    }

    // ---- partial sums: ds_add into dbuf acc (j=4kq+i, s=jl) ----
    {
      const int base = pb + kq*4*17 + jl;
#pragma unroll
      for (int i=0;i<4;i++){
        atomicAdd(&accb[base + 0*272 + i*17], cR[i]);
        atomicAdd(&accb[base + 1*272 + i*17], cZ[i]);
      }
      if (w8 <= 2){
#pragma unroll
        for (int i=0;i<4;i++) atomicAdd(&accb[base + 2*272 + i*17], cNI[i]);
      }
      if (w8 >= 2){
#pragma unroll
        for (int i=0;i<4;i++) atomicAdd(&accb[base + 3*272 + i*17], cNH[i]);
      }
    }
    __syncthreads();                   // C: partials(t) complete (only barrier)

    // ---- rotating gate wave: sums -> gates -> store -> flag ----
    if (w8 == (t & 7)){
      unsigned hop[4];
#pragma unroll
      for (int i=0;i<4;i++){           // h_old (issue early, sc)
        const int s = 4*i + kq;
        CLOADI(hop[i], hc + (size_t)(b0+s)*H_ + w*JT + jl);
      }
      float SR[4],SZ[4],SNI[4],SNH[4];
#pragma unroll
      for (int i=0;i<4;i++){
        const int s = 4*i + kq;
        const int o = pb + jl*17 + s;
        SR[i]  = accb[o + 0*272];
        SZ[i]  = accb[o + 1*272];
        SNI[i] = accb[o + 2*272];
        SNH[i] = accb[o + 3*272];
      }
#pragma unroll
      for (int q=0;q<17;q++) accb[pb + q*64 + l] = 0.f;  // zero for t+2
      VWAIT0();                        // h_old arrived
#pragma unroll
      for (int i=0;i<4;i++){
        const int s = 4*i + kq;
        const float hold = __uint_as_float(hop[i] & 0xFFFF0000u)
                         + __uint_as_float(hop[i] << 16);
        const float r = sig_(SR[i] + br);
        const float z = sig_(SZ[i] + bz);
        const float n = tanh_(SNI[i] + bni + r*(SNH[i] + bnh));
        const float hnew = (1.0f - z)*n + z*hold;
        const unsigned short hh = bf16rn(hnew);
        const unsigned short l2 = bf16rn(hnew - __uint_as_float(((unsigned)hh)<<16));
        const unsigned packed = (((unsigned)hh)<<16) | (unsigned)l2;
        CSTOREU(hnx + (size_t)(b0+s)*H_ + w*JT + jl, packed);
      }
      asm volatile("s_waitcnt vmcnt(0)" ::: "memory");
      if (l == 0){
        int* fp = flags + g*WPG + w;
        const int fv = t + 1;
        CSTOREU(fp, fv);
      }
    }
    // waves != gate wave free-run into step t+1 (dbuf acc makes it safe).
  }
}

__global__ void head_k(const unsigned* __restrict__ h, const float* __restrict__ W_out,
                       const float* __restrict__ b_out, float* __restrict__ out)
{
  const int b = (int)blockIdx.x;
  const int l = (int)threadIdx.x;
  const unsigned* hp = h + (size_t)b*H_ + l*8;
  const float* wp = W_out + l*8;
  float a = 0.f;
#pragma unroll
  for (int q=0;q<8;q++){
    const unsigned p = hp[q];
    const float v = __uint_as_float(p & 0xFFFF0000u) + __uint_as_float(p << 16);
    a = fmaf(v, wp[q], a);
  }
#pragma unroll
  for (int m=1;m<64;m<<=1) a += __shfl_xor(a, m, 64);
  if (l == 0) out[b] = sig_(a + b_out[0]);
}

extern "C" void kernel_launch(void* const* d_in, const int* in_sizes, int n_in,
                              void* d_out, int out_size, void* d_ws, size_t ws_size,
                              hipStream_t stream)
{
  const float* x    = (const float*)d_in[0];
  const float* Wih  = (const float*)d_in[1];
  const float* Whh  = (const float*)d_in[2];
  const float* bias = (const float*)d_in[3];
  const float* bn   = (const float*)d_in[4];
  const float* Wout = (const float*)d_in[5];
  const float* bout = (const float*)d_in[6];
  float* out      = (float*)d_out;
  unsigned* h_buf = (unsigned*)d_ws;
  int* flags      = (int*)((char*)d_ws + (size_t)2*B_*H_*sizeof(unsigned));

  (void)hipMemsetAsync(d_ws, 0, (size_t)2*B_*H_*sizeof(unsigned) + 4096, stream);
  (void)hipFuncSetAttribute((const void*)rnn_persist,
                            hipFuncAttributeMaxDynamicSharedMemorySize, LDS_DYN);

  void* args[7];
  args[0]=(void*)&x;    args[1]=(void*)&Wih;  args[2]=(void*)&Whh; args[3]=(void*)&bias;
  args[4]=(void*)&bn;   args[5]=(void*)&h_buf; args[6]=(void*)&flags;
  hipError_t e = hipLaunchCooperativeKernel((const void*)rnn_persist,
                                            dim3(256), dim3(NT), args, LDS_DYN, stream);
  if (e != hipSuccess){
    (void)hipGetLastError();
    rnn_persist<<<dim3(256), dim3(NT), LDS_DYN, stream>>>(x, Wih, Whh, bias, bn, h_buf, flags);
  }
  // T_ even -> final h in hb0; kernel boundary makes h_buf coherent for head_k
  head_k<<<dim3(128), dim3(64), 0, stream>>>(h_buf, Wout, bout, out);
}

// Round 18
// 11486.134 us; speedup vs baseline: 1.1864x; 1.1864x over previous
//
#include <hip/hip_runtime.h>

// GRU  B=128, T=1024, IN=256, H=512, OUT=1  (all fp32)
//
// v17 = v13 (passed, 11.8ms; pure IF-path sc0sc1 exchange) + two changes
// targeting IF coherence-point SERIALIZATION (the hypothesized 11us floor;
// r15-r17 proved the floor is not compute, not barriers, not L2 scope):
//  (1) MAILBOX FLAGS: producer wave0 lanes 0-31 store t+1 into 32 per-
//      consumer blocks (mbox[g][c][w], blocks 128B apart -> 32 distinct
//      sectors). Consumer wave0 polls ITS OWN private 128B block -- one
//      poller per sector, no serialization; s_sleep(1); barrier-P hand-off
//      (v10-proven). Previously: 32 wgs hammered the SAME 2 sectors.
//  (2) SKEWED h-stage: thread reads chunk (c+w)&31 of sample (ss+w)&15 so
//      the 32 wgs sweep the group h-tile from different offsets instead of
//      32 synchronized readers per sector.
// Everything else v13-verbatim (validated): split-bf16 3-pass MFMA, A-hi
// VGPR / A-lo LDS, U staged in LDS (hi/lo, pitch 776), ds_add acc, gate
// phase tid<256, packed (hi<<16|lo) h, separate head kernel. L2-scope
// experiment (v15/v16) abandoned per r16 pre-commitment.

#define B_    128
#define T_    1024
#define IN_   256
#define H_    512
#define NG    8
#define WPG   32
#define SGRP  16
#define JT    16
#define NT    512
#define RWU   776                          // U row pitch (bf16 elems); *2B = 1552
#define U_HI_OFF   0
#define U_LO_OFF   (SGRP*RWU*2)            // 24,832
#define WLO_OFF    (2*SGRP*RWU*2)          // 49,664
#define ACC_OFF    (WLO_OFF + 8*9*64*16)   // 123,392
#define LDS_DYN    (ACC_OFF + 4*16*17*4)   // 127,744 B

typedef __attribute__((ext_vector_type(8))) short bf16x8;
typedef __attribute__((ext_vector_type(4))) float f32x4;
union BCast { uint4 u; bf16x8 b; unsigned short s[8]; };

#define MFMA(a,b,c) __builtin_amdgcn_mfma_f32_16x16x32_bf16((a),(b),(c),0,0,0)

__device__ __forceinline__ float sig_(float v){ return 1.0f/(1.0f + __expf(-v)); }
__device__ __forceinline__ float tanh_(float v){
  float e = __expf(2.0f*v);
  return 1.0f - 2.0f/(e + 1.0f);
}
__device__ __forceinline__ unsigned short bf16rn(float f){
  unsigned u = __float_as_uint(f);
  return (unsigned short)((u + 0x7FFFu + ((u>>16)&1u)) >> 16);
}

// IF-coherent ops (sc0 sc1, v13/v14-proven). Data operands <=64-bit except
// 128-bit OUTPUTS.
#define CLOADU4(dst, p) asm volatile("global_load_dwordx4 %0, %1, off sc0 sc1" : "=v"(dst) : "v"(p) : "memory")
#define CLOADI(dst, p)  asm volatile("global_load_dword %0, %1, off sc0 sc1"   : "=v"(dst) : "v"(p) : "memory")
#define CSTOREU(p, v)   asm volatile("global_store_dword %0, %1, off sc0 sc1"  :: "v"(p), "v"(v) : "memory")
#define VWAIT0()        do{ asm volatile("s_waitcnt vmcnt(0)" ::: "memory"); __builtin_amdgcn_sched_barrier(0); }while(0)

// poll MY private mailbox block: 32 slots, one per producer. Single poller
// per sector -> aggressive s_sleep(1); guard 1<<22 (~0.5s) => no spurious trips.
__device__ __forceinline__ int poll_mbox(const int* blk, int lane, int target){
  const int* fp = blk + (lane & 31);
  int guard = 0;
  for (;;){
    int fv;
    CLOADI(fv, fp);
    asm volatile("s_waitcnt vmcnt(0)" ::: "memory");
    if (__all(fv >= target)) return 0;
    __builtin_amdgcn_s_sleep(1);
    if (++guard > (1<<22)) return 1;
  }
}

__global__ void __launch_bounds__(NT, 2)
rnn_persist(const float* __restrict__ x, const float* __restrict__ W_ih,
            const float* __restrict__ W_hh, const float* __restrict__ bias,
            const float* __restrict__ bias_n, unsigned* __restrict__ h_buf,
            int* __restrict__ mbox)
{
  extern __shared__ char lds[];
  unsigned short* Uhi = (unsigned short*)(lds + U_HI_OFF);
  unsigned short* Ulo = (unsigned short*)(lds + U_LO_OFF);
  char*  Wlo  = lds + WLO_OFF;
  float* accb = (float*)(lds + ACC_OFF);

  const int bid = (int)blockIdx.x;
  const int g   = bid & (NG-1);
  const int w   = bid >> 3;
  const int tid = (int)threadIdx.x;
  const int w8  = tid >> 6;            // wave [0,8)
  const int l   = tid & 63;            // lane
  const int jl  = l & 15;              // frag row/col lane index
  const int kq  = l >> 4;              // k-quarter [0,4)
  const int b0  = g*SGRP;
  const int jg_l = w*JT + jl;
  const int lane = tid & 63;

  // ---- init: A-fragments. hi -> 36 VGPRs; lo -> LDS (frag-order) ----
  bf16x8 ahi[9];
#pragma unroll
  for (int ci=0; ci<3; ci++){
    const int c = 3*w8 + ci;
#pragma unroll
    for (int gi=0; gi<3; gi++){
      const int f = 3*ci + gi;
      const int grow = gi*H_ + jg_l;
      const float* p = (c < 8)
        ? (W_ih + (size_t)grow*IN_ + (32*c + 8*kq))
        : (W_hh + (size_t)grow*H_  + (32*c - 256 + 8*kq));
      const float4 v0 = *(const float4*)p;
      const float4 v1 = *(const float4*)(p+4);
      const float vv[8] = {v0.x,v0.y,v0.z,v0.w,v1.x,v1.y,v1.z,v1.w};
      BCast hi8, lo8;
#pragma unroll
      for (int i=0;i<8;i++){
        const unsigned short h = bf16rn(vv[i]);
        hi8.s[i] = h;
        lo8.s[i] = bf16rn(vv[i] - __uint_as_float(((unsigned)h)<<16));
      }
      ahi[f] = hi8.b;
      *(bf16x8*)(Wlo + ((size_t)(w8*9 + f)*64 + l)*16) = lo8.b;
    }
  }
  // biases for gate threads (j = tid&15)
  float br, bz, bni, bnh;
  { const int jj = w*JT + (tid & 15);
    br = bias[jj]; bz = bias[H_+jj]; bni = bias[2*H_+jj]; bnh = bias_n[jj]; }
  __syncthreads();                     // Wlo visible

  int* const mymbox = mbox + (g*WPG + w)*32;   // my private 128B flag block

  unsigned* const hb0 = h_buf;
  unsigned* const hb1 = h_buf + (size_t)B_*H_;
  int dead = 0;

  for (int t=0; t<T_; ++t){
    const unsigned* hc = (t & 1) ? hb1 : hb0;
    unsigned*      hnx = (t & 1) ? hb0 : hb1;

    // ---- zero acc buffer (prev gate phase ended at barrier D) ----
    for (int i=tid; i<4*16*17; i+=NT) accb[i] = 0.f;

    // ---- x-stage (flag-independent): fp32 -> bf16 hi/lo -> U[0:256) ----
    {
      const int ss = tid>>5, c2 = tid&31;
      const float* xp = x + ((size_t)(b0+ss)*T_ + (size_t)t)*IN_ + c2*8;
      const float4 a = *(const float4*)xp;
      const float4 b = *(const float4*)(xp+4);
      const float vv[8] = {a.x,a.y,a.z,a.w,b.x,b.y,b.z,b.w};
      unsigned hw[4], lw[4];
#pragma unroll
      for (int q=0;q<4;q++){
        const unsigned short h0 = bf16rn(vv[2*q]);
        const unsigned short h1 = bf16rn(vv[2*q+1]);
        const float f0 = __uint_as_float(((unsigned)h0)<<16);
        const float f1 = __uint_as_float(((unsigned)h1)<<16);
        const unsigned short l0 = bf16rn(vv[2*q]-f0);
        const unsigned short l1 = bf16rn(vv[2*q+1]-f1);
        hw[q] = (unsigned)h0 | ((unsigned)h1<<16);
        lw[q] = (unsigned)l0 | ((unsigned)l1<<16);
      }
      *(uint4*)((char*)Uhi + ss*1552 + c2*16) = make_uint4(hw[0],hw[1],hw[2],hw[3]);
      *(uint4*)((char*)Ulo + ss*1552 + c2*16) = make_uint4(lw[0],lw[1],lw[2],lw[3]);
    }

    // ---- wave0 polls MY private mailbox; others wait at barrier P ----
    if (tid < 64 && t > 0 && !dead) dead = poll_mbox(mymbox, lane, t);
    __syncthreads();                   // P: h^t globally visible

    // ---- h-stage (SKEWED): packed u32 -> split hi/lo -> U[256:768) ----
    {
      const int ss = ((tid>>5) + w) & 15;      // skewed sample
      const int c2 = ((tid&31) + w) & 31;      // skewed chunk
      const unsigned* hp = hc + (size_t)(b0+ss)*H_ + c2*16;
      uint4 p0,p1,p2,p3;
      CLOADU4(p0, hp); CLOADU4(p1, hp+4); CLOADU4(p2, hp+8); CLOADU4(p3, hp+12);
      VWAIT0();
      const unsigned P[16] = {p0.x,p0.y,p0.z,p0.w, p1.x,p1.y,p1.z,p1.w,
                              p2.x,p2.y,p2.z,p2.w, p3.x,p3.y,p3.z,p3.w};
      unsigned hwv[8], lwv[8];
#pragma unroll
      for (int q=0;q<8;q++){
        hwv[q] = (P[2*q]>>16) | (P[2*q+1] & 0xFFFF0000u);
        lwv[q] = (P[2*q] & 0xFFFFu) | (P[2*q+1]<<16);
      }
      char* dh = (char*)Uhi + ss*1552 + 512 + c2*32;
      char* dl = (char*)Ulo + ss*1552 + 512 + c2*32;
      *(uint4*)dh      = make_uint4(hwv[0],hwv[1],hwv[2],hwv[3]);
      *(uint4*)(dh+16) = make_uint4(hwv[4],hwv[5],hwv[6],hwv[7]);
      *(uint4*)dl      = make_uint4(lwv[0],lwv[1],lwv[2],lwv[3]);
      *(uint4*)(dl+16) = make_uint4(lwv[4],lwv[5],lwv[6],lwv[7]);
    }
    __syncthreads();                   // B: U complete

    // ---- MFMA: 3 chunks x {r,z,ni|nh} x 3 passes ----
    f32x4 cR = {0,0,0,0}, cZ = {0,0,0,0}, cNI = {0,0,0,0}, cNH = {0,0,0,0};
#pragma unroll
    for (int ci=0; ci<3; ci++){
      const int c = 3*w8 + ci;
      const bf16x8 bhi = *(const bf16x8*)((char*)Uhi + jl*1552 + 64*c + 16*kq);
      const bf16x8 blo = *(const bf16x8*)((char*)Ulo + jl*1552 + 64*c + 16*kq);
      const bf16x8 aloR = *(const bf16x8*)(Wlo + ((size_t)(w8*9+3*ci+0)*64 + l)*16);
      const bf16x8 aloZ = *(const bf16x8*)(Wlo + ((size_t)(w8*9+3*ci+1)*64 + l)*16);
      const bf16x8 aloN = *(const bf16x8*)(Wlo + ((size_t)(w8*9+3*ci+2)*64 + l)*16);
      cR = MFMA(ahi[3*ci+0], bhi, cR);
      cR = MFMA(ahi[3*ci+0], blo, cR);
      cR = MFMA(aloR,        bhi, cR);
      cZ = MFMA(ahi[3*ci+1], bhi, cZ);
      cZ = MFMA(ahi[3*ci+1], blo, cZ);
      cZ = MFMA(aloZ,        bhi, cZ);
      if (c < 8){
        cNI = MFMA(ahi[3*ci+2], bhi, cNI);
        cNI = MFMA(ahi[3*ci+2], blo, cNI);
        cNI = MFMA(aloN,        bhi, cNI);
      } else {
        cNH = MFMA(ahi[3*ci+2], bhi, cNH);
        cNH = MFMA(ahi[3*ci+2], blo, cNH);
        cNH = MFMA(aloN,        bhi, cNH);
      }
    }
    // ---- cross-wave combine: ds_add_f32 into accb[4][16][17] ----
    {
      const int base = (kq*4)*17 + jl;
#pragma unroll
      for (int i=0;i<4;i++){
        atomicAdd(&accb[0*272 + base + i*17], cR[i]);
        atomicAdd(&accb[1*272 + base + i*17], cZ[i]);
      }
      if (w8 <= 2){
#pragma unroll
        for (int i=0;i<4;i++) atomicAdd(&accb[2*272 + base + i*17], cNI[i]);
      }
      if (w8 >= 2){
#pragma unroll
        for (int i=0;i<4;i++) atomicAdd(&accb[3*272 + base + i*17], cNH[i]);
      }
    }
    __syncthreads();                   // C: sums complete

    // ---- gates (256 threads): s = tid>>4, j = tid&15 ----
    if (tid < 256){
      const int s = tid>>4, j = tid&15;
      const float SR  = accb[0*272 + j*17 + s];
      const float SZ  = accb[1*272 + j*17 + s];
      const float SNI = accb[2*272 + j*17 + s];
      const float SNH = accb[3*272 + j*17 + s];
      const int hidx = 256 + w*JT + j;
      const float hold = __uint_as_float(((unsigned)Uhi[s*RWU + hidx])<<16)
                       + __uint_as_float(((unsigned)Ulo[s*RWU + hidx])<<16);
      const float r = sig_(SR + br);
      const float z = sig_(SZ + bz);
      const float n = tanh_(SNI + bni + r*(SNH + bnh));
      const float hnew = (1.0f - z)*n + z*hold;
      const unsigned short hh = bf16rn(hnew);
      const float fh = __uint_as_float(((unsigned)hh)<<16);
      const unsigned short ll2 = bf16rn(hnew - fh);
      const unsigned packed = (((unsigned)hh)<<16) | (unsigned)ll2;
      CSTOREU(hnx + (size_t)(b0+s)*H_ + w*JT + j, packed);
    }
    asm volatile("s_waitcnt vmcnt(0)" ::: "memory");
    __syncthreads();                   // D: all hnew stores drained
    // ---- mailbox broadcast: lane c -> consumer c's block, slot w ----
    if (tid < 32){
      int* fp = mbox + (g*WPG + tid)*32 + w;
      const int fv = t + 1;
      CSTOREU(fp, fv);
    }
  }
}

__global__ void head_k(const unsigned* __restrict__ h, const float* __restrict__ W_out,
                       const float* __restrict__ b_out, float* __restrict__ out)
{
  const int b = (int)blockIdx.x;       // 128 blocks, one sample each
  const int l = (int)threadIdx.x;      // 64 lanes
  const unsigned* hp = h + (size_t)b*H_ + l*8;
  const float* wp = W_out + l*8;
  float a = 0.f;
#pragma unroll
  for (int q=0;q<8;q++){
    const unsigned p = hp[q];
    const float v = __uint_as_float(p & 0xFFFF0000u) + __uint_as_float(p << 16);
    a = fmaf(v, wp[q], a);
  }
#pragma unroll
  for (int m=1;m<64;m<<=1) a += __shfl_xor(a, m, 64);
  if (l == 0) out[b] = sig_(a + b_out[0]);
}

extern "C" void kernel_launch(void* const* d_in, const int* in_sizes, int n_in,
                              void* d_out, int out_size, void* d_ws, size_t ws_size,
                              hipStream_t stream)
{
  const float* x    = (const float*)d_in[0];
  const float* Wih  = (const float*)d_in[1];
  const float* Whh  = (const float*)d_in[2];
  const float* bias = (const float*)d_in[3];
  const float* bn   = (const float*)d_in[4];
  const float* Wout = (const float*)d_in[5];
  const float* bout = (const float*)d_in[6];
  float* out      = (float*)d_out;
  unsigned* h_buf = (unsigned*)d_ws;                                     // 512 KB (2 bufs)
  int* mbox       = (int*)((char*)d_ws + (size_t)2*B_*H_*sizeof(unsigned)); // 32 KB

  // zero h0 (packed 0 == 0.0f) + mailboxes every launch
  (void)hipMemsetAsync(d_ws, 0, (size_t)2*B_*H_*sizeof(unsigned) + 8*WPG*32*4 + 4096, stream);

  (void)hipFuncSetAttribute((const void*)rnn_persist,
                            hipFuncAttributeMaxDynamicSharedMemorySize, LDS_DYN);

  void* args[7];
  args[0]=(void*)&x;    args[1]=(void*)&Wih;  args[2]=(void*)&Whh; args[3]=(void*)&bias;
  args[4]=(void*)&bn;   args[5]=(void*)&h_buf; args[6]=(void*)&mbox;
  hipError_t e = hipLaunchCooperativeKernel((const void*)rnn_persist,
                                            dim3(256), dim3(NT), args, LDS_DYN, stream);
  if (e != hipSuccess){
    (void)hipGetLastError();
    rnn_persist<<<dim3(256), dim3(NT), LDS_DYN, stream>>>(x, Wih, Whh, bias, bn, h_buf, mbox);
  }
  // T_ even -> final h in hb0; kernel boundary makes h_buf coherent for head_k
  head_k<<<dim3(128), dim3(64), 0, stream>>>(h_buf, Wout, bout, out);
}